// Round 10
// baseline (94.559 us; speedup 1.0000x reference)
//
#include <hip/hip_runtime.h>
#include <math.h>

// Problem constants (from reference)
#define Bb 4
#define Ss 256
#define Hh 768
#define Ee 200
#define Rr 200
#define Dd 25
#define NET 9                  // NUM_ENT_TYPES
#define NRT 5                  // NUM_REL_TYPES
#define ENT_REPR 1561          // Dd + 2*Hh
#define REL_REPR 2354          // 2*Dd + 3*Hh
#define SPAD 1568              // LDS row stride for span_w (16B-aligned rows)
#define RPAD 2368              // LDS row stride for rel_w
#define TPB 192                // 3 waves; thread owns one float4 channel column
#define H4 192                 // Hh/4
#define KENT 8                 // entity items per block
#define KREL 4                 // relation items per block
#define NBLK_REL (Bb*Rr/KREL)  // 200
#define NBLK_ENT (Bb*Ee/KENT)  // 100
// dynamic LDS: max(ent, rel) = (NET*SPAD + KENT*3*NET) floats = 57312 B
#define SMEM_BYTES ((NET*SPAD + KENT*3*NET) * 4)

// Self-contained single kernel, no d_ws (ws handoff diverges under graph
// replay — round 6). Key idea vs rounds 7-9 (all ~35us): amortize the weight
// matrix (staged once per block into LDS) over 8/4 items, and keep the
// barrier count per block at 2 INDEPENDENT of item count — all pool loads
// for all items issue in one barrier-free phase (no per-item vmcnt drains).
//
// Masks are contiguous spans (len in [1,29], start in [0,226)). Masked
// maxpool == max over [first,last] clamped with 0.

__device__ __forceinline__ float4 max4(float4 a, float4 b) {
    return make_float4(fmaxf(a.x, b.x), fmaxf(a.y, b.y),
                       fmaxf(a.z, b.z), fmaxf(a.w, b.w));
}
__device__ __forceinline__ float dot4(float4 a, float4 b) {
    return a.x*b.x + a.y*b.y + a.z*b.z + a.w*b.w;
}

// Wave-local span decode from one int4 (4 mask positions) per lane.
__device__ __forceinline__ void span_wave(int4 m, int lane,
                                          int& first, int& last, int& length)
{
    const int p = lane * 4;
    int cnt = (m.x != 0) + (m.y != 0) + (m.z != 0) + (m.w != 0);
    int fm = m.x ? p : (m.y ? p+1 : (m.z ? p+2 : (m.w ? p+3 : 1024)));
    int lm = m.w ? p+3 : (m.z ? p+2 : (m.y ? p+1 : (m.x ? p : -1)));
    #pragma unroll
    for (int o = 32; o > 0; o >>= 1) {
        cnt += __shfl_xor(cnt, o, 64);
        fm   = min(fm, __shfl_xor(fm, o, 64));
        lm   = max(lm, __shfl_xor(lm, o, 64));
    }
    first = fm; last = lm; length = cnt;
}

// Pool 4 items simultaneously: 8 loads in flight per iteration (2 rows/item).
// Tail rows clamp the ADDRESS (idempotent under max) — no OOB, no predicates.
__device__ __forceinline__ void pool_quad(const float4* __restrict__ lb4,
    int col, int f0, int l0, int f1, int l1, int f2, int l2, int f3, int l3,
    float4& a0, float4& a1, float4& a2, float4& a3)
{
    const float4 z = make_float4(0.f, 0.f, 0.f, 0.f);
    a0 = a1 = a2 = a3 = z;                       // 0-clamp built in
    const int n = max(max(l0 - f0, l1 - f1), max(l2 - f2, l3 - f3));
    for (int s = 0; s <= n; s += 2) {
        const float4 v00 = lb4[(size_t)min(f0 + s,     l0) * H4 + col];
        const float4 v01 = lb4[(size_t)min(f0 + s + 1, l0) * H4 + col];
        const float4 v10 = lb4[(size_t)min(f1 + s,     l1) * H4 + col];
        const float4 v11 = lb4[(size_t)min(f1 + s + 1, l1) * H4 + col];
        const float4 v20 = lb4[(size_t)min(f2 + s,     l2) * H4 + col];
        const float4 v21 = lb4[(size_t)min(f2 + s + 1, l2) * H4 + col];
        const float4 v30 = lb4[(size_t)min(f3 + s,     l3) * H4 + col];
        const float4 v31 = lb4[(size_t)min(f3 + s + 1, l3) * H4 + col];
        a0 = max4(a0, max4(v00, v01));
        a1 = max4(a1, max4(v10, v11));
        a2 = max4(a2, max4(v20, v21));
        a3 = max4(a3, max4(v30, v31));
    }
}

__global__ __launch_bounds__(TPB) void spert_fused(
    const float4* __restrict__ lhs4,     // B,S,H4
    const int*   __restrict__ ent_mask,  // B,E,S
    const int*   __restrict__ relations, // B,R,2
    const int*   __restrict__ rel_mask,  // B,R,S
    const float* __restrict__ size_emb,  // 100,D
    const float* __restrict__ span_w,    // NET,ENT_REPR
    const float* __restrict__ span_b,    // NET
    const float* __restrict__ rel_w,     // NRT,REL_REPR
    const float* __restrict__ rel_b,     // NRT
    float* __restrict__ ent_logit,       // B,E,NET
    float* __restrict__ rel_logit)       // B,R,NRT
{
    extern __shared__ float smem[];
    const int tid  = threadIdx.x;
    const int wave = tid >> 6;
    const int lane = tid & 63;

    if (blockIdx.x < NBLK_REL) {
        // ================= relation block: KREL items =================
        float* s_w    = smem;                    // NRT x RPAD
        float* s_part = smem + NRT * RPAD;       // [KREL][3][NRT]

        const int item0 = blockIdx.x * KREL;     // 4 consecutive, same b
        const int b  = item0 / Rr;
        const int r0 = item0 % Rr;
        const float4* lb4 = lhs4 + (size_t)b * Ss * H4;

        // ---- phase A (barrier-free): masks, decodes, pools, staging ----
        int2 ee[KREL];
        #pragma unroll
        for (int i = 0; i < KREL; ++i)
            ee[i] = ((const int2*)relations)[(size_t)b*Rr + r0 + i];

        int4 mc[KREL], m1[KREL], m2[KREL];
        #pragma unroll
        for (int i = 0; i < KREL; ++i) {
            mc[i] = ((const int4*)(rel_mask + (size_t)(b*Rr + r0 + i)*Ss))[lane];
            m1[i] = ((const int4*)(ent_mask + (size_t)(b*Ee + ee[i].x)*Ss))[lane];
            m2[i] = ((const int4*)(ent_mask + (size_t)(b*Ee + ee[i].y)*Ss))[lane];
        }
        int fc[KREL], lc[KREL], nc[KREL];
        int f1[KREL], l1[KREL], n1[KREL];
        int f2[KREL], l2[KREL], n2[KREL];
        #pragma unroll
        for (int i = 0; i < KREL; ++i) {
            span_wave(mc[i], lane, fc[i], lc[i], nc[i]);
            span_wave(m1[i], lane, f1[i], l1[i], n1[i]);
            span_wave(m2[i], lane, f2[i], l2[i], n2[i]);
        }

        float4 cp[KREL], ap[KREL], dp[KREL];
        pool_quad(lb4, tid, fc[0], lc[0], fc[1], lc[1], fc[2], lc[2], fc[3], lc[3],
                  cp[0], cp[1], cp[2], cp[3]);
        pool_quad(lb4, tid, f1[0], l1[0], f1[1], l1[1], f1[2], l1[2], f1[3], l1[3],
                  ap[0], ap[1], ap[2], ap[3]);
        pool_quad(lb4, tid, f2[0], l2[0], f2[1], l2[1], f2[2], l2[2], f2[3], l2[3],
                  dp[0], dp[1], dp[2], dp[3]);

        float sz1[KREL], sz2[KREL];
        #pragma unroll
        for (int i = 0; i < KREL; ++i) {
            sz1[i] = (tid < Dd) ? size_emb[n1[i] * Dd + tid] : 0.0f;
            sz2[i] = (tid < Dd) ? size_emb[n2[i] * Dd + tid] : 0.0f;
        }

        // stage rel_w -> LDS (padded rows). 11770 floats = 2942 quads + 2.
        {
            const float4* src4 = (const float4*)rel_w;
            for (int k4 = tid; k4 < (NRT * REL_REPR) / 4; k4 += TPB) {
                const float4 v = src4[k4];
                const float* ve = (const float*)&v;
                #pragma unroll
                for (int e = 0; e < 4; ++e) {
                    const int kk = 4 * k4 + e;
                    const int t  = kk / REL_REPR;
                    s_w[t * RPAD + (kk - t * REL_REPR)] = ve[e];
                }
            }
            if (tid < 2)   // tail elements 11768, 11769 (row 4, cols 2352+tid)
                s_w[4 * RPAD + 2352 + tid] = rel_w[11768 + tid];
        }
        __syncthreads();

        // ---- phase C (barrier-free): LDS weights x all items ----
        #pragma unroll
        for (int t = 0; t < NRT; ++t) {
            const float4* w4 = (const float4*)(s_w + t * RPAD);
            const float4 wc = w4[tid];
            const float4 wa = w4[192 + tid];
            const float4 wd = w4[384 + tid];
            const float w31 = (tid < Dd) ? s_w[t * RPAD + 3*Hh + tid] : 0.0f;
            const float w32 = (tid < Dd) ? s_w[t * RPAD + 3*Hh + Dd + tid] : 0.0f;
            float sm[KREL];
            #pragma unroll
            for (int i = 0; i < KREL; ++i)
                sm[i] = dot4(cp[i], wc) + dot4(ap[i], wa) + dot4(dp[i], wd)
                      + sz1[i] * w31 + sz2[i] * w32;
            #pragma unroll
            for (int o = 32; o > 0; o >>= 1) {
                #pragma unroll
                for (int i = 0; i < KREL; ++i)
                    sm[i] += __shfl_xor(sm[i], o, 64);
            }
            if (lane == 0) {
                #pragma unroll
                for (int i = 0; i < KREL; ++i)
                    s_part[(i * 3 + wave) * NRT + t] = sm[i];
            }
        }
        __syncthreads();
        if (tid < KREL * NRT) {
            const int i = tid / NRT, t = tid % NRT;
            rel_logit[(size_t)(b*Rr + r0 + i)*NRT + t] =
                s_part[(i*3 + 0)*NRT + t] + s_part[(i*3 + 1)*NRT + t]
              + s_part[(i*3 + 2)*NRT + t] + rel_b[t];
        }
    } else {
        // ================= entity block: KENT items =================
        float* s_w    = smem;                    // NET x SPAD
        float* s_part = smem + NET * SPAD;       // [KENT][3][NET]

        const int bi    = blockIdx.x - NBLK_REL; // 0..99
        const int item0 = bi * KENT;             // 8 consecutive, same b
        const int b  = item0 / Ee;
        const int e0 = item0 % Ee;
        const float4* lb4 = lhs4 + (size_t)b * Ss * H4;

        // ---- phase A (barrier-free) ----
        const float4 cx = lb4[tid];              // ctx = lhs[b,0,:], shared

        int4 mk[KENT];
        #pragma unroll
        for (int i = 0; i < KENT; ++i)
            mk[i] = ((const int4*)(ent_mask + (size_t)(b*Ee + e0 + i)*Ss))[lane];
        int fs[KENT], ls[KENT], ln[KENT];
        #pragma unroll
        for (int i = 0; i < KENT; ++i)
            span_wave(mk[i], lane, fs[i], ls[i], ln[i]);

        float4 vp[KENT];
        pool_quad(lb4, tid, fs[0], ls[0], fs[1], ls[1], fs[2], ls[2], fs[3], ls[3],
                  vp[0], vp[1], vp[2], vp[3]);
        pool_quad(lb4, tid, fs[4], ls[4], fs[5], ls[5], fs[6], ls[6], fs[7], ls[7],
                  vp[4], vp[5], vp[6], vp[7]);

        float sz[KENT];
        #pragma unroll
        for (int i = 0; i < KENT; ++i)
            sz[i] = (tid < Dd) ? size_emb[ln[i] * Dd + tid] : 0.0f;

        // stage span_w -> LDS (padded rows). 14049 floats = 3512 quads + 1.
        {
            const float4* src4 = (const float4*)span_w;
            for (int k4 = tid; k4 < (NET * ENT_REPR) / 4; k4 += TPB) {
                const float4 v = src4[k4];
                const float* ve = (const float*)&v;
                #pragma unroll
                for (int e = 0; e < 4; ++e) {
                    const int kk = 4 * k4 + e;
                    const int t  = kk / ENT_REPR;
                    s_w[t * SPAD + (kk - t * ENT_REPR)] = ve[e];
                }
            }
            if (tid == 0)  // tail element 14048 (row 8, col 1560)
                s_w[8 * SPAD + 1560] = span_w[14048];
        }
        __syncthreads();

        // ---- phase C (barrier-free) ----
        #pragma unroll
        for (int t = 0; t < NET; ++t) {
            const float4* w4 = (const float4*)(s_w + t * SPAD);
            const float4 wa = w4[tid];
            const float4 wb = w4[192 + tid];
            const float w2 = (tid < Dd) ? s_w[t * SPAD + 2*Hh + tid] : 0.0f;
            const float base = dot4(cx, wb);
            float sm[KENT];
            #pragma unroll
            for (int i = 0; i < KENT; ++i)
                sm[i] = dot4(vp[i], wa) + base + sz[i] * w2;
            #pragma unroll
            for (int o = 32; o > 0; o >>= 1) {
                #pragma unroll
                for (int i = 0; i < KENT; ++i)
                    sm[i] += __shfl_xor(sm[i], o, 64);
            }
            if (lane == 0) {
                #pragma unroll
                for (int i = 0; i < KENT; ++i)
                    s_part[(i * 3 + wave) * NET + t] = sm[i];
            }
        }
        __syncthreads();
        if (tid < KENT * NET) {
            const int i = tid / NET, t = tid % NET;
            ent_logit[(size_t)(b*Ee + e0 + i)*NET + t] =
                s_part[(i*3 + 0)*NET + t] + s_part[(i*3 + 1)*NET + t]
              + s_part[(i*3 + 2)*NET + t] + span_b[t];
        }
    }
}

extern "C" void kernel_launch(void* const* d_in, const int* in_sizes, int n_in,
                              void* d_out, int out_size, void* d_ws, size_t ws_size,
                              hipStream_t stream) {
    const float* lhs       = (const float*)d_in[0];  // B,S,H
    const int*   ent_mask  = (const int*)  d_in[1];  // B,E,S
    const int*   relations = (const int*)  d_in[2];  // B,R,2
    const int*   rel_mask  = (const int*)  d_in[3];  // B,R,S
    const float* size_emb  = (const float*)d_in[4];  // 100,25
    const float* span_w    = (const float*)d_in[5];  // 9,1561
    const float* span_b    = (const float*)d_in[6];  // 9
    const float* rel_w     = (const float*)d_in[7];  // 5,2354
    const float* rel_b     = (const float*)d_in[8];  // 5

    float* ent_logit = (float*)d_out;                     // B*E*NET = 7200
    float* rel_logit = (float*)d_out + (size_t)Bb*Ee*NET; // B*R*NRT = 4000

    spert_fused<<<NBLK_REL + NBLK_ENT, TPB, SMEM_BYTES, stream>>>(
        (const float4*)lhs, ent_mask, relations, rel_mask, size_emb,
        span_w, span_b, rel_w, rel_b, ent_logit, rel_logit);
}